// Round 5
// baseline (267.357 us; speedup 1.0000x reference)
//
#include <hip/hip_runtime.h>
#include <math.h>

#define B_   4
#define T_   512
#define TAU_ 512
#define L_   1024
#define DM_  1024
#define H_   16
#define D_   64

typedef short  s16x8 __attribute__((ext_vector_type(8)));   // 8 bf16 MFMA frag
typedef ushort u16x4 __attribute__((ext_vector_type(4)));
typedef float  f32x4 __attribute__((ext_vector_type(4)));

#define SC_LOG2 0.18033688011f   // 0.125 * log2(e): softmax runs in exp2 domain

__device__ __forceinline__ ushort f2bf(float x) {   // RNE float->bf16 bits
  uint u = __float_as_uint(x);
  u += 0x7fffu + ((u >> 16) & 1u);
  return (ushort)(u >> 16);
}
__device__ __forceinline__ float bf2f(ushort u) {
  return __uint_as_float(((uint)u) << 16);
}
// XOR-swizzle for bf16 [rows][64] LDS tiles (128B rows): permute 16B slots by row&7
__device__ __forceinline__ int sw64(int row, int col) {
  return row * 64 + (col ^ ((row & 7) << 3));
}

// ---------------------------------------------------------------------------
// Fused preprocessing: [0,4096) LayerNorm rows -> bf16 xn;
// [4096,8192) phi table; [8192,13312) weight fp32->bf16 casts.
// ---------------------------------------------------------------------------
__global__ __launch_bounds__(256) void prep_kernel(
    const float* __restrict__ inp, const float* __restrict__ mem,
    const float* __restrict__ gamma, const float* __restrict__ beta,
    ushort* __restrict__ xn, ushort* __restrict__ phi,
    const float* __restrict__ wq, ushort* __restrict__ wqb,
    const float* __restrict__ wp, ushort* __restrict__ wpb,
    const float* __restrict__ wo, ushort* __restrict__ wob) {
  int blk = blockIdx.x;
  int t = threadIdx.x;
  if (blk < 4096) {                    // ---- LayerNorm ----
    int row = blk;                     // b*L + l
    int b = row >> 10, l = row & 1023;
    const float* src = (l < TAU_)
        ? mem + ((size_t)b * TAU_ + l) * DM_
        : inp + ((size_t)b * T_ + (l - TAU_)) * DM_;
    float4 v = *(const float4*)(src + t * 4);
    float s  = v.x + v.y + v.z + v.w;
    float s2 = v.x * v.x + v.y * v.y + v.z * v.z + v.w * v.w;
#pragma unroll
    for (int off = 32; off > 0; off >>= 1) {
      s  += __shfl_down(s, off);
      s2 += __shfl_down(s2, off);
    }
    __shared__ float red[8];
    __shared__ float stat[2];
    int wid = t >> 6;
    if ((t & 63) == 0) { red[wid * 2] = s; red[wid * 2 + 1] = s2; }
    __syncthreads();
    if (t == 0) {
      float ts  = red[0] + red[2] + red[4] + red[6];
      float ts2 = red[1] + red[3] + red[5] + red[7];
      float mu  = ts * (1.0f / DM_);
      float var = ts2 * (1.0f / DM_) - mu * mu;
      stat[0] = mu;
      stat[1] = 1.0f / sqrtf(var + 1e-5f);
    }
    __syncthreads();
    float mu = stat[0], rstd = stat[1];
    float4 g  = *(const float4*)(gamma + t * 4);
    float4 be = *(const float4*)(beta  + t * 4);
    u16x4 o;
    o[0] = f2bf((v.x - mu) * rstd * g.x + be.x);
    o[1] = f2bf((v.y - mu) * rstd * g.y + be.y);
    o[2] = f2bf((v.z - mu) * rstd * g.z + be.z);
    o[3] = f2bf((v.w - mu) * rstd * g.w + be.w);
    *(u16x4*)(xn + (size_t)row * DM_ + t * 4) = o;
  } else if (blk < 8192) {             // ---- phi ----
    int idx = (blk - 4096) * 256 + t;  // 0 .. 1M-1
    int m = idx >> 10, c = idx & 1023;
    float p = (float)(1023 - m);
    int cc = (c < 512) ? c : c - 512;
    float invf = __expf(-((float)(2 * cc) * (1.0f / 1024.0f)) * 9.210340371976184f);
    float a = p * invf;
    phi[idx] = f2bf((c < 512) ? sinf(a) : cosf(a));
  } else {                             // ---- weight casts ----
    int i = (blk - 8192) * 256 + t;    // float4-group index, < 1310720
    const float* src; ushort* dst; int off;
    if (i < 786432)       { src = wq; dst = wqb; off = i; }
    else if (i < 1048576) { src = wp; dst = wpb; off = i - 786432; }
    else                  { src = wo; dst = wob; off = i - 1048576; }
    float4 v = *(const float4*)(src + (size_t)off * 4);
    u16x4 o = { f2bf(v.x), f2bf(v.y), f2bf(v.z), f2bf(v.w) };
    *(u16x4*)(dst + (size_t)off * 4) = o;
  }
}

// ---------------------------------------------------------------------------
// bf16 MFMA NT GEMM body (m97 structure, 128x128 tile, BK=32).
// ---------------------------------------------------------------------------
template <typename CT>
__device__ __forceinline__ void gemm_nt_body(
    const ushort* __restrict__ A, const ushort* __restrict__ B,
    CT* __restrict__ C, int M, int N, int K, int bx, int by) {
  __shared__ __attribute__((aligned(16))) ushort As[128 * 32];
  __shared__ __attribute__((aligned(16))) ushort Bs[128 * 32];
  int t = threadIdx.x;
  int w = t >> 6, lane = t & 63, g = lane >> 4, low = lane & 15;
  int wr = w >> 1, wc = w & 1;               // wave 2x2 grid, 64x64 each
  int m0 = by * 128, n0 = bx * 128;
  f32x4 acc[4][4] = {};

  for (int kt = 0; kt < K; kt += 32) {
    __syncthreads();                         // prev-iter LDS reads done
#pragma unroll
    for (int q = 0; q < 2; ++q) {
      int f = t + q * 256;                   // chunk 0..511 (16B each)
      int row = f >> 2;
      int gslot = (f & 3) ^ ((row >> 1) & 3);
      const ushort* ga = A + (size_t)(m0 + row) * K + kt + gslot * 8;
      const ushort* gb = B + (size_t)(n0 + row) * K + kt + gslot * 8;
      __builtin_amdgcn_global_load_lds(
          (const __attribute__((address_space(1))) void*)ga,
          (__attribute__((address_space(3))) void*)&As[(q * 256 + w * 64) * 8],
          16, 0, 0);
      __builtin_amdgcn_global_load_lds(
          (const __attribute__((address_space(1))) void*)gb,
          (__attribute__((address_space(3))) void*)&Bs[(q * 256 + w * 64) * 8],
          16, 0, 0);
    }
    __syncthreads();                         // vmcnt(0) drain: tiles ready

    s16x8 af[4], bfr[4];
#pragma unroll
    for (int mi = 0; mi < 4; ++mi) {
      int row = wr * 64 + mi * 16 + low;
      af[mi] = *(const s16x8*)&As[row * 32 + ((g ^ ((row >> 1) & 3)) * 8)];
    }
#pragma unroll
    for (int ni = 0; ni < 4; ++ni) {
      int col = wc * 64 + ni * 16 + low;
      bfr[ni] = *(const s16x8*)&Bs[col * 32 + ((g ^ ((col >> 1) & 3)) * 8)];
    }
#pragma unroll
    for (int mi = 0; mi < 4; ++mi)
#pragma unroll
      for (int ni = 0; ni < 4; ++ni)
        acc[mi][ni] = __builtin_amdgcn_mfma_f32_16x16x32_bf16(
            af[mi], bfr[ni], acc[mi][ni], 0, 0, 0);
  }
#pragma unroll
  for (int mi = 0; mi < 4; ++mi)
#pragma unroll
    for (int ni = 0; ni < 4; ++ni)
#pragma unroll
      for (int r = 0; r < 4; ++r) {
        int m = m0 + wr * 64 + mi * 16 + 4 * g + r;
        int n = n0 + wc * 64 + ni * 16 + low;
        if constexpr (sizeof(CT) == 2)
          C[(size_t)m * N + n] = f2bf(acc[mi][ni][r]);
        else
          C[(size_t)m * N + n] = acc[mi][ni][r];
      }
}

// QKV GEMM (768 tiles) + R GEMM (64 tiles) in one 832-block dispatch.
// Bijective XCD swizzle (832 = 8 x 104): each XCD gets 104 consecutive tiles.
__global__ __launch_bounds__(256) void qkv_r_gemm(
    const ushort* __restrict__ xnb, const ushort* __restrict__ wqb,
    ushort* __restrict__ qkvB,
    const ushort* __restrict__ phib, const ushort* __restrict__ wpb,
    ushort* __restrict__ RmB) {
  int orig = blockIdx.x;
  int id = (orig & 7) * 104 + (orig >> 3);
  if (id < 768)
    gemm_nt_body<ushort>(xnb, wqb, qkvB, 4096, 3072, 1024, id % 24, id / 24);
  else {
    id -= 768;
    gemm_nt_body<ushort>(phib, wpb, RmB, 1024, 1024, 1024, id % 8, id / 8);
  }
}

__global__ __launch_bounds__(256) void out_gemm(
    const ushort* __restrict__ attnb, const ushort* __restrict__ wob,
    float* __restrict__ out) {
  int orig = blockIdx.x;                     // 128 = 8 x 16
  int id = (orig & 7) * 16 + (orig >> 3);
  gemm_nt_body<float>(attnb, wob, out, 2048, 1024, 1024, id % 8, id / 8);
}

// ---------------------------------------------------------------------------
// Transpose the V third of qkv (bf16) into vtg[(b*16+h)*64 + d][L].
// ---------------------------------------------------------------------------
__global__ __launch_bounds__(256) void vtrans_kernel(
    const ushort* __restrict__ qkv, ushort* __restrict__ vtg) {
  __shared__ ushort vs[64 * 65];
  int bid = blockIdx.x;
  int lt = bid & 15;
  int h  = (bid >> 4) & 15;
  int b  = bid >> 8;
  int l0 = lt * 64;
  int t = threadIdx.x;
#pragma unroll
  for (int q = 0; q < 2; ++q) {
    int c = t + q * 256;
    int row = c >> 3, sl = c & 7;
    s16x8 v = *(const s16x8*)(qkv +
        (size_t)(b * L_ + l0 + row) * 3072 + 2048 + h * 64 + sl * 8);
#pragma unroll
    for (int e = 0; e < 8; ++e) vs[row * 65 + sl * 8 + e] = (ushort)v[e];
  }
  __syncthreads();
#pragma unroll
  for (int q = 0; q < 2; ++q) {
    int c = t + q * 256;
    int d = c >> 3, sl = c & 7;
    s16x8 o;
#pragma unroll
    for (int e = 0; e < 8; ++e) o[e] = (short)vs[(sl * 8 + e) * 65 + d];
    *(s16x8*)(vtg + (size_t)((b * 16 + h) * 64 + d) * 1024 + l0 + sl * 8) = o;
  }
}

// ---------------------------------------------------------------------------
// MFMA bf16 flash attention with rel-shift.
// K/V double-buffered via global_load_lds; R fragments read DIRECTLY from
// global (L2-resident, per-wave windows have no cross-wave reuse -> staging
// was pure overhead). LDS 40KB -> 4 blocks/CU (16 waves, 4/SIMD) for 2x
// latency hiding; __launch_bounds__(256,4) caps VGPR at 128 to hold it.
// XCD swizzle groups the 8 i-blocks of each (b,h) on one XCD (~4MB working
// set = one XCD L2).
// ---------------------------------------------------------------------------
__global__ __launch_bounds__(256, 4) void attn_mfma_kernel(
    const ushort* __restrict__ qkv, const ushort* __restrict__ Rm,
    const ushort* __restrict__ vtg,
    const float* __restrict__ uvar, const float* __restrict__ vvar,
    ushort* __restrict__ attn) {
  __shared__ __attribute__((aligned(16))) ushort Ks[2][64 * 64];
  __shared__ __attribute__((aligned(16))) ushort Vt[2][64 * 64];
  __shared__ __attribute__((aligned(16))) ushort Pp[4][16 * 64];

  int t   = threadIdx.x;
  int w   = t >> 6;          // wave 0..3
  int lw  = t & 63;
  int g   = lw >> 4;         // k-group 0..3
  int low = lw & 15;

  int orig = blockIdx.x;     // 512 = 8 x 64: XCD x owns (b,h) groups 8x..8x+7
  int bid  = (orig & 7) * 64 + (orig >> 3);
  int bi  = bid & 7;
  int h   = (bid >> 3) & 15;
  int b   = bid >> 7;
  int i0  = bi * 64;
  int lb_w = 48 - 16 * w;    // wave's P m-window base

  auto stage = [&](int buf, int tl) {
    int j0s = tl * 64;
#pragma unroll
    for (int q = 0; q < 2; ++q) {
      int c = t + q * 256;                  // 16B chunk id 0..511
      int row = c >> 3;
      int sl = (c & 7) ^ (row & 7);         // inverse slot swizzle on source
      const ushort* srck = qkv + (size_t)(b * L_ + j0s + row) * 3072 +
                           1024 + h * 64 + sl * 8;
      __builtin_amdgcn_global_load_lds(
          (const __attribute__((address_space(1))) void*)srck,
          (__attribute__((address_space(3))) void*)&Ks[buf][(q * 256 + w * 64) * 8],
          16, 0, 0);
      const ushort* srcv = vtg + (size_t)((b * 16 + h) * 64 + row) * 1024 +
                           j0s + sl * 8;
      __builtin_amdgcn_global_load_lds(
          (const __attribute__((address_space(1))) void*)srcv,
          (__attribute__((address_space(3))) void*)&Vt[buf][(q * 256 + w * 64) * 8],
          16, 0, 0);
    }
  };

  // Q fragments (bf16 source + fp32 u/v), loaded once
  int iq = i0 + 16 * w + low;
  s16x8 qu[2], qv[2];
  {
    const ushort* qrow = qkv + (size_t)(b * L_ + TAU_ + iq) * 3072 + h * 64;
    const float* ur = uvar + h * 64;
    const float* vr = vvar + h * 64;
#pragma unroll
    for (int kc = 0; kc < 2; ++kc) {
      int dbase = kc * 32 + 8 * g;
#pragma unroll
      for (int e = 0; e < 8; ++e) {
        float q = bf2f(qrow[dbase + e]);
        qu[kc][e] = (short)f2bf(q + ur[dbase + e]);
        qv[kc][e] = (short)f2bf(q + vr[dbase + e]);
      }
    }
  }

  f32x4 O[4] = {};
  float mreg[4] = {-INFINITY, -INFINITY, -INFINITY, -INFINITY};
  float lreg[4] = {0.f, 0.f, 0.f, 0.f};

  int ntiles = 9 + bi;       // covers j <= TAU + i0 + 63 exactly
  stage(0, 0);
  __syncthreads();           // drains vmcnt: tile 0 ready
  int cur = 0;
  for (int tile = 0; tile < ntiles; ++tile) {
    int j0 = tile * 64;
    if (tile + 1 < ntiles) stage(cur ^ 1, tile + 1);   // prefetch next K/V

    // ---- issue R fragment loads from global (L2-hot) ----
    int mb = j0 + 448 - i0;                  // >= 0 for all blocks
    s16x8 rb[10];                            // [kc*5+mt]
#pragma unroll
    for (int kc = 0; kc < 2; ++kc)
#pragma unroll
      for (int mt = 0; mt < 5; ++mt) {
        int m = mb + lb_w + mt * 16 + low;
        m = (m > 1023) ? 1023 : m;           // over-range rows are masked later
        rb[kc * 5 + mt] = *(const s16x8*)(Rm + (size_t)m * 1024 + h * 64 +
                                          kc * 32 + 8 * g);
      }

    // ---- QK^T (LDS) ----
    f32x4 s[4] = {};
#pragma unroll
    for (int jt = 0; jt < 4; ++jt) {
#pragma unroll
      for (int kc = 0; kc < 2; ++kc) {
        s16x8 kb = *(const s16x8*)&Ks[cur][sw64(jt * 16 + low, kc * 32 + 8 * g)];
        s[jt] = __builtin_amdgcn_mfma_f32_16x16x32_bf16(qu[kc], kb, s[jt], 0, 0, 0);
      }
    }
    // ---- P = (q+v)·R over the wave's 80-col m-window ----
    f32x4 p[5] = {};
#pragma unroll
    for (int kc = 0; kc < 2; ++kc)
#pragma unroll
      for (int mt = 0; mt < 5; ++mt)
        p[mt] = __builtin_amdgcn_mfma_f32_16x16x32_bf16(
            qv[kc], rb[kc * 5 + mt], p[mt], 0, 0, 0);

    // ---- rel-shift via shfl + scale(+mask) in exp2 domain ----
    bool fullvalid = (j0 + 63 <= TAU_ + i0 + 16 * w);   // wave-uniform
#pragma unroll
    for (int r = 0; r < 4; ++r) {
      int iL = 4 * g + r;
      int src = g * 16 + ((low + 15 - iL) & 15);   // D-layout: col=lane&15
      float sh0 = __shfl(p[0][r], src);
      float sh1 = __shfl(p[1][r], src);
      float sh2 = __shfl(p[2][r], src);
      float sh3 = __shfl(p[3][r], src);
      float sh4 = __shfl(p[4][r], src);
      bool lo = (low <= iL);
      float po0 = lo ? sh0 : sh1;
      float po1 = lo ? sh1 : sh2;
      float po2 = lo ? sh2 : sh3;
      float po3 = lo ? sh3 : sh4;
      if (fullvalid) {
        s[0][r] = (s[0][r] + po0) * SC_LOG2;
        s[1][r] = (s[1][r] + po1) * SC_LOG2;
        s[2][r] = (s[2][r] + po2) * SC_LOG2;
        s[3][r] = (s[3][r] + po3) * SC_LOG2;
      } else {
        int lim = TAU_ + i0 + 16 * w + iL;
        s[0][r] = (j0 +  0 + low <= lim) ? (s[0][r] + po0) * SC_LOG2 : -1e30f;
        s[1][r] = (j0 + 16 + low <= lim) ? (s[1][r] + po1) * SC_LOG2 : -1e30f;
        s[2][r] = (j0 + 32 + low <= lim) ? (s[2][r] + po2) * SC_LOG2 : -1e30f;
        s[3][r] = (j0 + 48 + low <= lim) ? (s[3][r] + po3) * SC_LOG2 : -1e30f;
      }
    }
    // ---- online softmax (exp2 domain) ----
#pragma unroll
    for (int r = 0; r < 4; ++r) {
      float mx = fmaxf(fmaxf(s[0][r], s[1][r]), fmaxf(s[2][r], s[3][r]));
      mx = fmaxf(mx, __shfl_xor(mx, 1));
      mx = fmaxf(mx, __shfl_xor(mx, 2));
      mx = fmaxf(mx, __shfl_xor(mx, 4));
      mx = fmaxf(mx, __shfl_xor(mx, 8));
      float mn = fmaxf(mreg[r], mx);
      float alpha = exp2f(mreg[r] - mn);
      mreg[r] = mn;
      float sum = 0.f;
#pragma unroll
      for (int jt = 0; jt < 4; ++jt) {
        float pe = exp2f(s[jt][r] - mn);
        s[jt][r] = pe;
        sum += pe;
      }
      sum += __shfl_xor(sum, 1);
      sum += __shfl_xor(sum, 2);
      sum += __shfl_xor(sum, 4);
      sum += __shfl_xor(sum, 8);
      lreg[r] = lreg[r] * alpha + sum;
      O[0][r] *= alpha; O[1][r] *= alpha; O[2][r] *= alpha; O[3][r] *= alpha;
    }
    // ---- P -> bf16 LDS (C-layout -> A-layout transpose) ----
#pragma unroll
    for (int jt = 0; jt < 4; ++jt)
#pragma unroll
      for (int r = 0; r < 4; ++r)
        Pp[w][sw64(4 * g + r, jt * 16 + low)] = f2bf(s[jt][r]);
    asm volatile("s_waitcnt lgkmcnt(0)" ::: "memory");
    s16x8 pa0 = *(const s16x8*)&Pp[w][sw64(low, 8 * g)];
    s16x8 pa1 = *(const s16x8*)&Pp[w][sw64(low, 32 + 8 * g)];
    // ---- PV ----
#pragma unroll
    for (int dt = 0; dt < 4; ++dt) {
      s16x8 v0 = *(const s16x8*)&Vt[cur][sw64(dt * 16 + low, 8 * g)];
      s16x8 v1 = *(const s16x8*)&Vt[cur][sw64(dt * 16 + low, 32 + 8 * g)];
      O[dt] = __builtin_amdgcn_mfma_f32_16x16x32_bf16(pa0, v0, O[dt], 0, 0, 0);
      O[dt] = __builtin_amdgcn_mfma_f32_16x16x32_bf16(pa1, v1, O[dt], 0, 0, 0);
    }
    __syncthreads();         // all LDS reads done + next-tile DMA landed
    cur ^= 1;
  }
  // epilogue: normalize, store bf16 for the out-GEMM
  float inv[4];
#pragma unroll
  for (int r = 0; r < 4; ++r) inv[r] = 1.0f / lreg[r];
#pragma unroll
  for (int dt = 0; dt < 4; ++dt)
#pragma unroll
    for (int r = 0; r < 4; ++r)
      attn[((size_t)(b * T_ + i0 + 16 * w + 4 * g + r)) * 1024 +
           h * 64 + dt * 16 + low] = f2bf(O[dt][r] * inv[r]);
}

// ---------------------------------------------------------------------------
extern "C" void kernel_launch(void* const* d_in, const int* in_sizes, int n_in,
                              void* d_out, int out_size, void* d_ws, size_t ws_size,
                              hipStream_t stream) {
  const float* inputs = (const float*)d_in[0];
  const float* memory = (const float*)d_in[1];
  const float* w_qkv  = (const float*)d_in[2];
  const float* w_pos  = (const float*)d_in[3];
  const float* w_out  = (const float*)d_in[4];
  const float* uvar   = (const float*)d_in[5];
  const float* vvar   = (const float*)d_in[6];
  const float* gamma  = (const float*)d_in[7];
  const float* beta   = (const float*)d_in[8];
  float* out = (float*)d_out;

  // workspace layout, all bf16 (56.6 MB)
  ushort* qkvB = (ushort*)d_ws;                       // 4096*3072
  ushort* xnb  = qkvB + (size_t)4096 * 3072;          // 4096*1024
  ushort* phib = xnb  + (size_t)4096 * 1024;          // 1024*1024
  ushort* RmB  = phib + (size_t)1024 * 1024;          // 1024*1024
  ushort* wqb  = RmB  + (size_t)1024 * 1024;          // 3072*1024
  ushort* wpb  = wqb  + (size_t)3072 * 1024;          // 1024*1024
  ushort* wob  = wpb  + (size_t)1024 * 1024;          // 1024*1024
  ushort* vtg  = wob  + (size_t)1024 * 1024;          // 4096*1024 (V^T)
  ushort* attnb = xnb;                                // reuse after QKV GEMM

  prep_kernel<<<13312, 256, 0, stream>>>(inputs, memory, gamma, beta, xnb,
                                         phib, w_qkv, wqb, w_pos, wpb, w_out, wob);
  qkv_r_gemm<<<832, 256, 0, stream>>>(xnb, wqb, qkvB, phib, wpb, RmB);
  vtrans_kernel<<<B_ * H_ * 16, 256, 0, stream>>>(qkvB, vtg);
  attn_mfma_kernel<<<dim3(B_ * H_ * 8), 256, 0, stream>>>(qkvB, RmB, vtg, uvar, vvar, attnb);
  out_gemm<<<128, 256, 0, stream>>>(attnb, wob, out);
}

// Round 6
// 212.062 us; speedup vs baseline: 1.2607x; 1.2607x over previous
//
#include <hip/hip_runtime.h>
#include <math.h>

#define B_   4
#define T_   512
#define TAU_ 512
#define L_   1024
#define DM_  1024
#define H_   16
#define D_   64

typedef short  s16x8 __attribute__((ext_vector_type(8)));   // 8 bf16 MFMA frag
typedef ushort u16x4 __attribute__((ext_vector_type(4)));
typedef float  f32x4 __attribute__((ext_vector_type(4)));

__device__ __forceinline__ ushort f2bf(float x) {   // RNE float->bf16 bits
  uint u = __float_as_uint(x);
  u += 0x7fffu + ((u >> 16) & 1u);
  return (ushort)(u >> 16);
}
__device__ __forceinline__ float bf2f(ushort u) {
  return __uint_as_float(((uint)u) << 16);
}
// XOR-swizzle for bf16 [rows][64] LDS tiles (128B rows): permute 16B slots by row&7
__device__ __forceinline__ int sw64(int row, int col) {
  return row * 64 + (col ^ ((row & 7) << 3));
}

// ---------------------------------------------------------------------------
// Fused preprocessing: [0,4096) LayerNorm rows -> bf16 xn;
// [4096,8192) phi table; [8192,13312) weight fp32->bf16 casts.
// ---------------------------------------------------------------------------
__global__ __launch_bounds__(256) void prep_kernel(
    const float* __restrict__ inp, const float* __restrict__ mem,
    const float* __restrict__ gamma, const float* __restrict__ beta,
    ushort* __restrict__ xn, ushort* __restrict__ phi,
    const float* __restrict__ wq, ushort* __restrict__ wqb,
    const float* __restrict__ wp, ushort* __restrict__ wpb,
    const float* __restrict__ wo, ushort* __restrict__ wob) {
  int blk = blockIdx.x;
  int t = threadIdx.x;
  if (blk < 4096) {                    // ---- LayerNorm ----
    int row = blk;                     // b*L + l
    int b = row >> 10, l = row & 1023;
    const float* src = (l < TAU_)
        ? mem + ((size_t)b * TAU_ + l) * DM_
        : inp + ((size_t)b * T_ + (l - TAU_)) * DM_;
    float4 v = *(const float4*)(src + t * 4);
    float s  = v.x + v.y + v.z + v.w;
    float s2 = v.x * v.x + v.y * v.y + v.z * v.z + v.w * v.w;
#pragma unroll
    for (int off = 32; off > 0; off >>= 1) {
      s  += __shfl_down(s, off);
      s2 += __shfl_down(s2, off);
    }
    __shared__ float red[8];
    __shared__ float stat[2];
    int wid = t >> 6;
    if ((t & 63) == 0) { red[wid * 2] = s; red[wid * 2 + 1] = s2; }
    __syncthreads();
    if (t == 0) {
      float ts  = red[0] + red[2] + red[4] + red[6];
      float ts2 = red[1] + red[3] + red[5] + red[7];
      float mu  = ts * (1.0f / DM_);
      float var = ts2 * (1.0f / DM_) - mu * mu;
      stat[0] = mu;
      stat[1] = 1.0f / sqrtf(var + 1e-5f);
    }
    __syncthreads();
    float mu = stat[0], rstd = stat[1];
    float4 g  = *(const float4*)(gamma + t * 4);
    float4 be = *(const float4*)(beta  + t * 4);
    u16x4 o;
    o[0] = f2bf((v.x - mu) * rstd * g.x + be.x);
    o[1] = f2bf((v.y - mu) * rstd * g.y + be.y);
    o[2] = f2bf((v.z - mu) * rstd * g.z + be.z);
    o[3] = f2bf((v.w - mu) * rstd * g.w + be.w);
    *(u16x4*)(xn + (size_t)row * DM_ + t * 4) = o;
  } else if (blk < 8192) {             // ---- phi ----
    int idx = (blk - 4096) * 256 + t;  // 0 .. 1M-1
    int m = idx >> 10, c = idx & 1023;
    float p = (float)(1023 - m);
    int cc = (c < 512) ? c : c - 512;
    float invf = __expf(-((float)(2 * cc) * (1.0f / 1024.0f)) * 9.210340371976184f);
    float a = p * invf;
    phi[idx] = f2bf((c < 512) ? sinf(a) : cosf(a));
  } else {                             // ---- weight casts ----
    int i = (blk - 8192) * 256 + t;    // float4-group index, < 1310720
    const float* src; ushort* dst; int off;
    if (i < 786432)       { src = wq; dst = wqb; off = i; }
    else if (i < 1048576) { src = wp; dst = wpb; off = i - 786432; }
    else                  { src = wo; dst = wob; off = i - 1048576; }
    float4 v = *(const float4*)(src + (size_t)off * 4);
    u16x4 o = { f2bf(v.x), f2bf(v.y), f2bf(v.z), f2bf(v.w) };
    *(u16x4*)(dst + (size_t)off * 4) = o;
  }
}

// ---------------------------------------------------------------------------
// bf16 MFMA NT GEMM body: m97 structure, 128x128 tile, BK=64 (32 MFMAs per
// barrier-drain instead of 16 -> half the vmcnt(0)+barrier stalls at K=1024).
// LDS [128][64]bf16 linear (16KB each); both-sides slot swizzle: 8 16B-slots
// per row, slot ^= row&7 on pre-swizzled global source and on ds_read.
// ---------------------------------------------------------------------------
template <typename CT>
__device__ __forceinline__ void gemm_nt_body(
    const ushort* __restrict__ A, const ushort* __restrict__ B,
    CT* __restrict__ C, int M, int N, int K, int bx, int by) {
  __shared__ __attribute__((aligned(16))) ushort As[128 * 64];
  __shared__ __attribute__((aligned(16))) ushort Bs[128 * 64];
  int t = threadIdx.x;
  int w = t >> 6, lane = t & 63, g = lane >> 4, low = lane & 15;
  int wr = w >> 1, wc = w & 1;               // wave 2x2 grid, 64x64 each
  int m0 = by * 128, n0 = bx * 128;
  f32x4 acc[4][4] = {};

  for (int kt = 0; kt < K; kt += 64) {
    __syncthreads();                         // prev-iter LDS reads done
#pragma unroll
    for (int q = 0; q < 4; ++q) {
      int c = t + q * 256;                   // 16B chunk id 0..1023
      int row = c >> 3;
      int gslot = (c & 7) ^ (row & 7);       // inverse swizzle on source
      const ushort* ga = A + (size_t)(m0 + row) * K + kt + gslot * 8;
      const ushort* gb = B + (size_t)(n0 + row) * K + kt + gslot * 8;
      __builtin_amdgcn_global_load_lds(
          (const __attribute__((address_space(1))) void*)ga,
          (__attribute__((address_space(3))) void*)&As[(q * 256 + w * 64) * 8],
          16, 0, 0);
      __builtin_amdgcn_global_load_lds(
          (const __attribute__((address_space(1))) void*)gb,
          (__attribute__((address_space(3))) void*)&Bs[(q * 256 + w * 64) * 8],
          16, 0, 0);
    }
    __syncthreads();                         // vmcnt(0) drain: tiles ready

#pragma unroll
    for (int kc = 0; kc < 2; ++kc) {
      s16x8 af[4], bfr[4];
#pragma unroll
      for (int mi = 0; mi < 4; ++mi) {
        int row = wr * 64 + mi * 16 + low;
        af[mi] = *(const s16x8*)&As[row * 64 + (((4 * kc + g) ^ (row & 7)) * 8)];
      }
#pragma unroll
      for (int ni = 0; ni < 4; ++ni) {
        int col = wc * 64 + ni * 16 + low;
        bfr[ni] = *(const s16x8*)&Bs[col * 64 + (((4 * kc + g) ^ (col & 7)) * 8)];
      }
#pragma unroll
      for (int mi = 0; mi < 4; ++mi)
#pragma unroll
        for (int ni = 0; ni < 4; ++ni)
          acc[mi][ni] = __builtin_amdgcn_mfma_f32_16x16x32_bf16(
              af[mi], bfr[ni], acc[mi][ni], 0, 0, 0);
    }
  }
#pragma unroll
  for (int mi = 0; mi < 4; ++mi)
#pragma unroll
    for (int ni = 0; ni < 4; ++ni)
#pragma unroll
      for (int r = 0; r < 4; ++r) {
        int m = m0 + wr * 64 + mi * 16 + 4 * g + r;
        int n = n0 + wc * 64 + ni * 16 + low;
        if constexpr (sizeof(CT) == 2)
          C[(size_t)m * N + n] = f2bf(acc[mi][ni][r]);
        else
          C[(size_t)m * N + n] = acc[mi][ni][r];
      }
}

// QKV GEMM (768 tiles) + R GEMM (64 tiles) in one 832-block dispatch.
// Bijective XCD swizzle (832 = 8 x 104).
__global__ __launch_bounds__(256) void qkv_r_gemm(
    const ushort* __restrict__ xnb, const ushort* __restrict__ wqb,
    ushort* __restrict__ qkvB,
    const ushort* __restrict__ phib, const ushort* __restrict__ wpb,
    ushort* __restrict__ RmB) {
  int orig = blockIdx.x;
  int id = (orig & 7) * 104 + (orig >> 3);
  if (id < 768)
    gemm_nt_body<ushort>(xnb, wqb, qkvB, 4096, 3072, 1024, id % 24, id / 24);
  else {
    id -= 768;
    gemm_nt_body<ushort>(phib, wpb, RmB, 1024, 1024, 1024, id % 8, id / 8);
  }
}

__global__ __launch_bounds__(256) void out_gemm(
    const ushort* __restrict__ attnb, const ushort* __restrict__ wob,
    float* __restrict__ out) {
  int orig = blockIdx.x;                     // 128 = 8 x 16
  int id = (orig & 7) * 16 + (orig >> 3);
  gemm_nt_body<float>(attnb, wob, out, 2048, 1024, 1024, id % 8, id / 8);
}

// ---------------------------------------------------------------------------
// Transpose the V third of qkv (bf16) into vtg[(b*16+h)*64 + d][L].
// ---------------------------------------------------------------------------
__global__ __launch_bounds__(256) void vtrans_kernel(
    const ushort* __restrict__ qkv, ushort* __restrict__ vtg) {
  __shared__ ushort vs[64 * 65];
  int bid = blockIdx.x;
  int lt = bid & 15;
  int h  = (bid >> 4) & 15;
  int b  = bid >> 8;
  int l0 = lt * 64;
  int t = threadIdx.x;
#pragma unroll
  for (int q = 0; q < 2; ++q) {
    int c = t + q * 256;
    int row = c >> 3, sl = c & 7;
    s16x8 v = *(const s16x8*)(qkv +
        (size_t)(b * L_ + l0 + row) * 3072 + 2048 + h * 64 + sl * 8);
#pragma unroll
    for (int e = 0; e < 8; ++e) vs[row * 65 + sl * 8 + e] = (ushort)v[e];
  }
  __syncthreads();
#pragma unroll
  for (int q = 0; q < 2; ++q) {
    int c = t + q * 256;
    int d = c >> 3, sl = c & 7;
    s16x8 o;
#pragma unroll
    for (int e = 0; e < 8; ++e) o[e] = (short)vs[(sl * 8 + e) * 65 + d];
    *(s16x8*)(vtg + (size_t)((b * 16 + h) * 64 + d) * 1024 + l0 + sl * 8) = o;
  }
}

// ---------------------------------------------------------------------------
// MFMA bf16 flash attention with rel-shift — round-3 known-good version
// (56.7us): K/V/R double-buffered via global_load_lds, shfl rel-shift,
// one barrier per tile, no setprio, no launch-bounds cap, no XCD swizzle.
// ---------------------------------------------------------------------------
__global__ __launch_bounds__(256) void attn_mfma_kernel(
    const ushort* __restrict__ qkv, const ushort* __restrict__ Rm,
    const ushort* __restrict__ vtg,
    const float* __restrict__ uvar, const float* __restrict__ vvar,
    ushort* __restrict__ attn) {
  __shared__ __attribute__((aligned(16))) ushort Ks[2][64 * 64];
  __shared__ __attribute__((aligned(16))) ushort Vt[2][64 * 64];
  __shared__ __attribute__((aligned(16))) ushort Rs[2][128 * 64];
  __shared__ __attribute__((aligned(16))) ushort Pp[4][16 * 64];

  int t   = threadIdx.x;
  int w   = t >> 6;          // wave 0..3
  int lw  = t & 63;
  int g   = lw >> 4;         // k-group 0..3
  int low = lw & 15;

  int bid = blockIdx.x;
  int bi  = bid & 7;
  int h   = (bid >> 3) & 15;
  int b   = bid >> 7;
  int i0  = bi * 64;
  int lb_w = 48 - 16 * w;    // wave's P m-window base within Rs

  auto stage = [&](int buf, int tl) {
    int j0s = tl * 64;
#pragma unroll
    for (int q = 0; q < 2; ++q) {
      int c = t + q * 256;                  // 16B chunk id 0..511
      int row = c >> 3;
      int sl = (c & 7) ^ (row & 7);         // inverse slot swizzle on source
      const ushort* srck = qkv + (size_t)(b * L_ + j0s + row) * 3072 +
                           1024 + h * 64 + sl * 8;
      __builtin_amdgcn_global_load_lds(
          (const __attribute__((address_space(1))) void*)srck,
          (__attribute__((address_space(3))) void*)&Ks[buf][(q * 256 + w * 64) * 8],
          16, 0, 0);
      const ushort* srcv = vtg + (size_t)((b * 16 + h) * 64 + row) * 1024 +
                           j0s + sl * 8;
      __builtin_amdgcn_global_load_lds(
          (const __attribute__((address_space(1))) void*)srcv,
          (__attribute__((address_space(3))) void*)&Vt[buf][(q * 256 + w * 64) * 8],
          16, 0, 0);
    }
    int mb = j0s + 448 - i0;
#pragma unroll
    for (int q = 0; q < 4; ++q) {
      int c = t + q * 256;                  // chunk 0..1023
      int row = c >> 3;                     // R row 0..127
      int m = mb + row; m = (m > 1023) ? 1023 : m;
      int sl = (c & 7) ^ (row & 7);
      const ushort* srcr = Rm + (size_t)m * 1024 + h * 64 + sl * 8;
      __builtin_amdgcn_global_load_lds(
          (const __attribute__((address_space(1))) void*)srcr,
          (__attribute__((address_space(3))) void*)&Rs[buf][(q * 256 + w * 64) * 8],
          16, 0, 0);
    }
  };

  // Q fragments (bf16 source + fp32 u/v), loaded once
  int iq = i0 + 16 * w + low;
  s16x8 qu[2], qv[2];
  {
    const ushort* qrow = qkv + (size_t)(b * L_ + TAU_ + iq) * 3072 + h * 64;
    const float* ur = uvar + h * 64;
    const float* vr = vvar + h * 64;
#pragma unroll
    for (int kc = 0; kc < 2; ++kc) {
      int dbase = kc * 32 + 8 * g;
#pragma unroll
      for (int e = 0; e < 8; ++e) {
        float q = bf2f(qrow[dbase + e]);
        qu[kc][e] = (short)f2bf(q + ur[dbase + e]);
        qv[kc][e] = (short)f2bf(q + vr[dbase + e]);
      }
    }
  }

  f32x4 O[4] = {};
  float mreg[4] = {-INFINITY, -INFINITY, -INFINITY, -INFINITY};
  float lreg[4] = {0.f, 0.f, 0.f, 0.f};

  int ntiles = 9 + bi;       // covers j <= TAU + i0 + 63 exactly
  stage(0, 0);
  __syncthreads();           // drains vmcnt: tile 0 ready
  int cur = 0;
  for (int tile = 0; tile < ntiles; ++tile) {
    int j0 = tile * 64;
    if (tile + 1 < ntiles) stage(cur ^ 1, tile + 1);   // prefetch next

    // ---- QK^T ----
    f32x4 s[4] = {};
#pragma unroll
    for (int jt = 0; jt < 4; ++jt) {
#pragma unroll
      for (int kc = 0; kc < 2; ++kc) {
        s16x8 kb = *(const s16x8*)&Ks[cur][sw64(jt * 16 + low, kc * 32 + 8 * g)];
        s[jt] = __builtin_amdgcn_mfma_f32_16x16x32_bf16(qu[kc], kb, s[jt], 0, 0, 0);
      }
    }
    // ---- P = (q+v)·R over the wave's 80-col m-window ----
    f32x4 p[5] = {};
#pragma unroll
    for (int mt = 0; mt < 5; ++mt) {
#pragma unroll
      for (int kc = 0; kc < 2; ++kc) {
        s16x8 rb = *(const s16x8*)&Rs[cur][sw64(lb_w + mt * 16 + low, kc * 32 + 8 * g)];
        p[mt] = __builtin_amdgcn_mfma_f32_16x16x32_bf16(qv[kc], rb, p[mt], 0, 0, 0);
      }
    }
    // ---- rel-shift via shfl + mask ----
#pragma unroll
    for (int r = 0; r < 4; ++r) {
      int iL = 4 * g + r;
      int src = g * 16 + ((low + 15 - iL) & 15);   // D-layout: col=lane&15
      float sh0 = __shfl(p[0][r], src);
      float sh1 = __shfl(p[1][r], src);
      float sh2 = __shfl(p[2][r], src);
      float sh3 = __shfl(p[3][r], src);
      float sh4 = __shfl(p[4][r], src);
      bool lo = (low <= iL);
      float po0 = lo ? sh0 : sh1;
      float po1 = lo ? sh1 : sh2;
      float po2 = lo ? sh2 : sh3;
      float po3 = lo ? sh3 : sh4;
      int lim = TAU_ + i0 + 16 * w + iL;
      s[0][r] = (j0 +  0 + low <= lim) ? (s[0][r] + po0) * 0.125f : -1e30f;
      s[1][r] = (j0 + 16 + low <= lim) ? (s[1][r] + po1) * 0.125f : -1e30f;
      s[2][r] = (j0 + 32 + low <= lim) ? (s[2][r] + po2) * 0.125f : -1e30f;
      s[3][r] = (j0 + 48 + low <= lim) ? (s[3][r] + po3) * 0.125f : -1e30f;
    }
    // ---- online softmax ----
#pragma unroll
    for (int r = 0; r < 4; ++r) {
      float mx = fmaxf(fmaxf(s[0][r], s[1][r]), fmaxf(s[2][r], s[3][r]));
      mx = fmaxf(mx, __shfl_xor(mx, 1));
      mx = fmaxf(mx, __shfl_xor(mx, 2));
      mx = fmaxf(mx, __shfl_xor(mx, 4));
      mx = fmaxf(mx, __shfl_xor(mx, 8));
      float mn = fmaxf(mreg[r], mx);
      float alpha = __expf(mreg[r] - mn);
      mreg[r] = mn;
      float sum = 0.f;
#pragma unroll
      for (int jt = 0; jt < 4; ++jt) {
        float pe = __expf(s[jt][r] - mn);
        s[jt][r] = pe;
        sum += pe;
      }
      sum += __shfl_xor(sum, 1);
      sum += __shfl_xor(sum, 2);
      sum += __shfl_xor(sum, 4);
      sum += __shfl_xor(sum, 8);
      lreg[r] = lreg[r] * alpha + sum;
      O[0][r] *= alpha; O[1][r] *= alpha; O[2][r] *= alpha; O[3][r] *= alpha;
    }
    // ---- P -> bf16 LDS (C-layout -> A-layout transpose) ----
#pragma unroll
    for (int jt = 0; jt < 4; ++jt)
#pragma unroll
      for (int r = 0; r < 4; ++r)
        Pp[w][sw64(4 * g + r, jt * 16 + low)] = f2bf(s[jt][r]);
    asm volatile("s_waitcnt lgkmcnt(0)" ::: "memory");
    s16x8 pa0 = *(const s16x8*)&Pp[w][sw64(low, 8 * g)];
    s16x8 pa1 = *(const s16x8*)&Pp[w][sw64(low, 32 + 8 * g)];
    // ---- PV ----
#pragma unroll
    for (int dt = 0; dt < 4; ++dt) {
      s16x8 v0 = *(const s16x8*)&Vt[cur][sw64(dt * 16 + low, 8 * g)];
      s16x8 v1 = *(const s16x8*)&Vt[cur][sw64(dt * 16 + low, 32 + 8 * g)];
      O[dt] = __builtin_amdgcn_mfma_f32_16x16x32_bf16(pa0, v0, O[dt], 0, 0, 0);
      O[dt] = __builtin_amdgcn_mfma_f32_16x16x32_bf16(pa1, v1, O[dt], 0, 0, 0);
    }
    __syncthreads();         // all LDS reads done + next-tile DMA landed
    cur ^= 1;
  }
  // epilogue: normalize, store bf16 for the out-GEMM
  float inv[4];
#pragma unroll
  for (int r = 0; r < 4; ++r) inv[r] = 1.0f / lreg[r];
#pragma unroll
  for (int dt = 0; dt < 4; ++dt)
#pragma unroll
    for (int r = 0; r < 4; ++r)
      attn[((size_t)(b * T_ + i0 + 16 * w + 4 * g + r)) * 1024 +
           h * 64 + dt * 16 + low] = f2bf(O[dt][r] * inv[r]);
}

// ---------------------------------------------------------------------------
extern "C" void kernel_launch(void* const* d_in, const int* in_sizes, int n_in,
                              void* d_out, int out_size, void* d_ws, size_t ws_size,
                              hipStream_t stream) {
  const float* inputs = (const float*)d_in[0];
  const float* memory = (const float*)d_in[1];
  const float* w_qkv  = (const float*)d_in[2];
  const float* w_pos  = (const float*)d_in[3];
  const float* w_out  = (const float*)d_in[4];
  const float* uvar   = (const float*)d_in[5];
  const float* vvar   = (const float*)d_in[6];
  const float* gamma  = (const float*)d_in[7];
  const float* beta   = (const float*)d_in[8];
  float* out = (float*)d_out;

  // workspace layout, all bf16 (56.6 MB)
  ushort* qkvB = (ushort*)d_ws;                       // 4096*3072
  ushort* xnb  = qkvB + (size_t)4096 * 3072;          // 4096*1024
  ushort* phib = xnb  + (size_t)4096 * 1024;          // 1024*1024
  ushort* RmB  = phib + (size_t)1024 * 1024;          // 1024*1024
  ushort* wqb  = RmB  + (size_t)1024 * 1024;          // 3072*1024
  ushort* wpb  = wqb  + (size_t)3072 * 1024;          // 1024*1024
  ushort* wob  = wpb  + (size_t)1024 * 1024;          // 1024*1024
  ushort* vtg  = wob  + (size_t)1024 * 1024;          // 4096*1024 (V^T)
  ushort* attnb = xnb;                                // reuse after QKV GEMM

  prep_kernel<<<13312, 256, 0, stream>>>(inputs, memory, gamma, beta, xnb,
                                         phib, w_qkv, wqb, w_pos, wpb, w_out, wob);
  qkv_r_gemm<<<832, 256, 0, stream>>>(xnb, wqb, qkvB, phib, wpb, RmB);
  vtrans_kernel<<<B_ * H_ * 16, 256, 0, stream>>>(qkvB, vtg);
  attn_mfma_kernel<<<dim3(B_ * H_ * 8), 256, 0, stream>>>(qkvB, RmB, vtg, uvar, vvar, attnb);
  out_gemm<<<128, 256, 0, stream>>>(attnb, wob, out);
}

// Round 7
// 211.221 us; speedup vs baseline: 1.2658x; 1.0040x over previous
//
#include <hip/hip_runtime.h>
#include <math.h>

#define B_   4
#define T_   512
#define TAU_ 512
#define L_   1024
#define DM_  1024
#define H_   16
#define D_   64

typedef short  s16x8 __attribute__((ext_vector_type(8)));   // 8 bf16 MFMA frag
typedef ushort u16x4 __attribute__((ext_vector_type(4)));
typedef float  f32x4 __attribute__((ext_vector_type(4)));

__device__ __forceinline__ ushort f2bf(float x) {   // RNE float->bf16 bits
  uint u = __float_as_uint(x);
  u += 0x7fffu + ((u >> 16) & 1u);
  return (ushort)(u >> 16);
}
__device__ __forceinline__ float bf2f(ushort u) {
  return __uint_as_float(((uint)u) << 16);
}
// XOR-swizzle for bf16 [rows][64] LDS tiles (128B rows): permute 16B slots by row&7
__device__ __forceinline__ int sw64(int row, int col) {
  return row * 64 + (col ^ ((row & 7) << 3));
}
// DPP lane move within 16-lane rows (full-rate VALU, replaces ds_swizzle
// shuffles in reduction chains). 0xB1=quad xor1, 0x4E=quad xor2,
// 0x124=row_ror:4, 0x128=row_ror:8 (rotations are reduce-valid).
template <int CTRL>
__device__ __forceinline__ float dppmov(float x) {
  int xi = __float_as_int(x);
  return __int_as_float(
      __builtin_amdgcn_update_dpp(xi, xi, CTRL, 0xF, 0xF, false));
}

// ---------------------------------------------------------------------------
// Fused preprocessing: [0,4096) LayerNorm rows -> bf16 xn;
// [4096,8192) phi table; [8192,13312) weight fp32->bf16 casts.
// ---------------------------------------------------------------------------
__global__ __launch_bounds__(256) void prep_kernel(
    const float* __restrict__ inp, const float* __restrict__ mem,
    const float* __restrict__ gamma, const float* __restrict__ beta,
    ushort* __restrict__ xn, ushort* __restrict__ phi,
    const float* __restrict__ wq, ushort* __restrict__ wqb,
    const float* __restrict__ wp, ushort* __restrict__ wpb,
    const float* __restrict__ wo, ushort* __restrict__ wob) {
  int blk = blockIdx.x;
  int t = threadIdx.x;
  if (blk < 4096) {                    // ---- LayerNorm ----
    int row = blk;                     // b*L + l
    int b = row >> 10, l = row & 1023;
    const float* src = (l < TAU_)
        ? mem + ((size_t)b * TAU_ + l) * DM_
        : inp + ((size_t)b * T_ + (l - TAU_)) * DM_;
    float4 v = *(const float4*)(src + t * 4);
    float s  = v.x + v.y + v.z + v.w;
    float s2 = v.x * v.x + v.y * v.y + v.z * v.z + v.w * v.w;
#pragma unroll
    for (int off = 32; off > 0; off >>= 1) {
      s  += __shfl_down(s, off);
      s2 += __shfl_down(s2, off);
    }
    __shared__ float red[8];
    __shared__ float stat[2];
    int wid = t >> 6;
    if ((t & 63) == 0) { red[wid * 2] = s; red[wid * 2 + 1] = s2; }
    __syncthreads();
    if (t == 0) {
      float ts  = red[0] + red[2] + red[4] + red[6];
      float ts2 = red[1] + red[3] + red[5] + red[7];
      float mu  = ts * (1.0f / DM_);
      float var = ts2 * (1.0f / DM_) - mu * mu;
      stat[0] = mu;
      stat[1] = 1.0f / sqrtf(var + 1e-5f);
    }
    __syncthreads();
    float mu = stat[0], rstd = stat[1];
    float4 g  = *(const float4*)(gamma + t * 4);
    float4 be = *(const float4*)(beta  + t * 4);
    u16x4 o;
    o[0] = f2bf((v.x - mu) * rstd * g.x + be.x);
    o[1] = f2bf((v.y - mu) * rstd * g.y + be.y);
    o[2] = f2bf((v.z - mu) * rstd * g.z + be.z);
    o[3] = f2bf((v.w - mu) * rstd * g.w + be.w);
    *(u16x4*)(xn + (size_t)row * DM_ + t * 4) = o;
  } else if (blk < 8192) {             // ---- phi ----
    int idx = (blk - 4096) * 256 + t;  // 0 .. 1M-1
    int m = idx >> 10, c = idx & 1023;
    float p = (float)(1023 - m);
    int cc = (c < 512) ? c : c - 512;
    float invf = __expf(-((float)(2 * cc) * (1.0f / 1024.0f)) * 9.210340371976184f);
    float a = p * invf;
    phi[idx] = f2bf((c < 512) ? sinf(a) : cosf(a));
  } else {                             // ---- weight casts ----
    int i = (blk - 8192) * 256 + t;    // float4-group index, < 1310720
    const float* src; ushort* dst; int off;
    if (i < 786432)       { src = wq; dst = wqb; off = i; }
    else if (i < 1048576) { src = wp; dst = wpb; off = i - 786432; }
    else                  { src = wo; dst = wob; off = i - 1048576; }
    float4 v = *(const float4*)(src + (size_t)off * 4);
    u16x4 o = { f2bf(v.x), f2bf(v.y), f2bf(v.z), f2bf(v.w) };
    *(u16x4*)(dst + (size_t)off * 4) = o;
  }
}

// ---------------------------------------------------------------------------
// bf16 MFMA NT GEMM body: m97 structure, 128x128 tile, BK=64.
// ---------------------------------------------------------------------------
template <typename CT>
__device__ __forceinline__ void gemm_nt_body(
    const ushort* __restrict__ A, const ushort* __restrict__ B,
    CT* __restrict__ C, int M, int N, int K, int bx, int by) {
  __shared__ __attribute__((aligned(16))) ushort As[128 * 64];
  __shared__ __attribute__((aligned(16))) ushort Bs[128 * 64];
  int t = threadIdx.x;
  int w = t >> 6, lane = t & 63, g = lane >> 4, low = lane & 15;
  int wr = w >> 1, wc = w & 1;               // wave 2x2 grid, 64x64 each
  int m0 = by * 128, n0 = bx * 128;
  f32x4 acc[4][4] = {};

  for (int kt = 0; kt < K; kt += 64) {
    __syncthreads();                         // prev-iter LDS reads done
#pragma unroll
    for (int q = 0; q < 4; ++q) {
      int c = t + q * 256;                   // 16B chunk id 0..1023
      int row = c >> 3;
      int gslot = (c & 7) ^ (row & 7);       // inverse swizzle on source
      const ushort* ga = A + (size_t)(m0 + row) * K + kt + gslot * 8;
      const ushort* gb = B + (size_t)(n0 + row) * K + kt + gslot * 8;
      __builtin_amdgcn_global_load_lds(
          (const __attribute__((address_space(1))) void*)ga,
          (__attribute__((address_space(3))) void*)&As[(q * 256 + w * 64) * 8],
          16, 0, 0);
      __builtin_amdgcn_global_load_lds(
          (const __attribute__((address_space(1))) void*)gb,
          (__attribute__((address_space(3))) void*)&Bs[(q * 256 + w * 64) * 8],
          16, 0, 0);
    }
    __syncthreads();                         // vmcnt(0) drain: tiles ready

#pragma unroll
    for (int kc = 0; kc < 2; ++kc) {
      s16x8 af[4], bfr[4];
#pragma unroll
      for (int mi = 0; mi < 4; ++mi) {
        int row = wr * 64 + mi * 16 + low;
        af[mi] = *(const s16x8*)&As[row * 64 + (((4 * kc + g) ^ (row & 7)) * 8)];
      }
#pragma unroll
      for (int ni = 0; ni < 4; ++ni) {
        int col = wc * 64 + ni * 16 + low;
        bfr[ni] = *(const s16x8*)&Bs[col * 64 + (((4 * kc + g) ^ (col & 7)) * 8)];
      }
#pragma unroll
      for (int mi = 0; mi < 4; ++mi)
#pragma unroll
        for (int ni = 0; ni < 4; ++ni)
          acc[mi][ni] = __builtin_amdgcn_mfma_f32_16x16x32_bf16(
              af[mi], bfr[ni], acc[mi][ni], 0, 0, 0);
    }
  }
#pragma unroll
  for (int mi = 0; mi < 4; ++mi)
#pragma unroll
    for (int ni = 0; ni < 4; ++ni)
#pragma unroll
      for (int r = 0; r < 4; ++r) {
        int m = m0 + wr * 64 + mi * 16 + 4 * g + r;
        int n = n0 + wc * 64 + ni * 16 + low;
        if constexpr (sizeof(CT) == 2)
          C[(size_t)m * N + n] = f2bf(acc[mi][ni][r]);
        else
          C[(size_t)m * N + n] = acc[mi][ni][r];
      }
}

// QKV GEMM (768 tiles) + R GEMM (64 tiles) in one 832-block dispatch.
// Bijective XCD swizzle (832 = 8 x 104).
__global__ __launch_bounds__(256) void qkv_r_gemm(
    const ushort* __restrict__ xnb, const ushort* __restrict__ wqb,
    ushort* __restrict__ qkvB,
    const ushort* __restrict__ phib, const ushort* __restrict__ wpb,
    ushort* __restrict__ RmB) {
  int orig = blockIdx.x;
  int id = (orig & 7) * 104 + (orig >> 3);
  if (id < 768)
    gemm_nt_body<ushort>(xnb, wqb, qkvB, 4096, 3072, 1024, id % 24, id / 24);
  else {
    id -= 768;
    gemm_nt_body<ushort>(phib, wpb, RmB, 1024, 1024, 1024, id % 8, id / 8);
  }
}

__global__ __launch_bounds__(256) void out_gemm(
    const ushort* __restrict__ attnb, const ushort* __restrict__ wob,
    float* __restrict__ out) {
  int orig = blockIdx.x;                     // 128 = 8 x 16
  int id = (orig & 7) * 16 + (orig >> 3);
  gemm_nt_body<float>(attnb, wob, out, 2048, 1024, 1024, id % 8, id / 8);
}

// ---------------------------------------------------------------------------
// MFMA bf16 flash attention with rel-shift.
// vs round-6 known-good: (1) softmax reduces use DPP (VALU pipe) instead of
// ds_swizzle shuffles; (2) V is transposed in-kernel during staging
// (reg-load early, swizzled ds_write_b16 late) -> vtrans kernel + vtg buffer
// eliminated. K/R still double-buffered via global_load_lds.
// ---------------------------------------------------------------------------
__global__ __launch_bounds__(256) void attn_mfma_kernel(
    const ushort* __restrict__ qkv, const ushort* __restrict__ Rm,
    const float* __restrict__ uvar, const float* __restrict__ vvar,
    ushort* __restrict__ attn) {
  __shared__ __attribute__((aligned(16))) ushort Ks[2][64 * 64];
  __shared__ __attribute__((aligned(16))) ushort Vt[2][64 * 64];
  __shared__ __attribute__((aligned(16))) ushort Rs[2][128 * 64];
  __shared__ __attribute__((aligned(16))) ushort Pp[4][16 * 64];

  int t   = threadIdx.x;
  int w   = t >> 6;          // wave 0..3
  int lw  = t & 63;
  int g   = lw >> 4;         // k-group 0..3
  int low = lw & 15;

  int bid = blockIdx.x;
  int bi  = bid & 7;
  int h   = (bid >> 3) & 15;
  int b   = bid >> 7;
  int i0  = bi * 64;
  int lb_w = 48 - 16 * w;    // wave's P m-window base within Rs

  // K + R staging via global_load_lds (linear LDS dest, pre-swizzled source)
  auto stage_kr = [&](int buf, int tl) {
    int j0s = tl * 64;
#pragma unroll
    for (int q = 0; q < 2; ++q) {
      int c = t + q * 256;                  // 16B chunk id 0..511
      int row = c >> 3;
      int sl = (c & 7) ^ (row & 7);
      const ushort* srck = qkv + (size_t)(b * L_ + j0s + row) * 3072 +
                           1024 + h * 64 + sl * 8;
      __builtin_amdgcn_global_load_lds(
          (const __attribute__((address_space(1))) void*)srck,
          (__attribute__((address_space(3))) void*)&Ks[buf][(q * 256 + w * 64) * 8],
          16, 0, 0);
    }
    int mb = j0s + 448 - i0;
#pragma unroll
    for (int q = 0; q < 4; ++q) {
      int c = t + q * 256;                  // chunk 0..1023
      int row = c >> 3;                     // R row 0..127
      int m = mb + row; m = (m > 1023) ? 1023 : m;
      int sl = (c & 7) ^ (row & 7);
      const ushort* srcr = Rm + (size_t)m * 1024 + h * 64 + sl * 8;
      __builtin_amdgcn_global_load_lds(
          (const __attribute__((address_space(1))) void*)srcr,
          (__attribute__((address_space(3))) void*)&Rs[buf][(q * 256 + w * 64) * 8],
          16, 0, 0);
    }
  };

  // V staging: reg-load (issue early) ...
  int vj  = t & 63;                         // wave-local j column
  int vd0 = (t >> 6) * 8;                   // wave-uniform d base (0,8,16,24)
  float4 vreg[2];
  auto vload = [&](int tl) {
    const ushort* p = qkv + (size_t)(b * L_ + tl * 64 + vj) * 3072 + 2048 + h * 64;
    vreg[0] = *(const float4*)(p + vd0);
    vreg[1] = *(const float4*)(p + vd0 + 32);
  };
  // ... transpose-write late (d rows wave-uniform: 64 lanes x 2B = no conflict)
  auto vwrite = [&](int buf) {
#pragma unroll
    for (int it = 0; it < 2; ++it) {
      ushort vals[8];
      *(float4*)vals = vreg[it];
#pragma unroll
      for (int e = 0; e < 8; ++e) {
        int d = it * 32 + vd0 + e;
        Vt[buf][d * 64 + (vj ^ ((d & 7) << 3))] = vals[e];
      }
    }
  };

  // Q fragments (bf16 source + fp32 u/v), loaded once
  int iq = i0 + 16 * w + low;
  s16x8 qu[2], qv[2];
  {
    const ushort* qrow = qkv + (size_t)(b * L_ + TAU_ + iq) * 3072 + h * 64;
    const float* ur = uvar + h * 64;
    const float* vr = vvar + h * 64;
#pragma unroll
    for (int kc = 0; kc < 2; ++kc) {
      int dbase = kc * 32 + 8 * g;
#pragma unroll
      for (int e = 0; e < 8; ++e) {
        float q = bf2f(qrow[dbase + e]);
        qu[kc][e] = (short)f2bf(q + ur[dbase + e]);
        qv[kc][e] = (short)f2bf(q + vr[dbase + e]);
      }
    }
  }

  f32x4 O[4] = {};
  float mreg[4] = {-INFINITY, -INFINITY, -INFINITY, -INFINITY};
  float lreg[4] = {0.f, 0.f, 0.f, 0.f};

  int ntiles = 9 + bi;       // covers j <= TAU + i0 + 63 exactly
  stage_kr(0, 0);
  vload(0);
  vwrite(0);                 // compiler inserts vmcnt wait on vreg use
  __syncthreads();           // drains DMA + LDS writes: tile 0 ready
  int cur = 0;
  for (int tile = 0; tile < ntiles; ++tile) {
    int j0 = tile * 64;
    bool more = (tile + 1 < ntiles);
    if (more) { stage_kr(cur ^ 1, tile + 1); vload(tile + 1); }

    // ---- QK^T ----
    f32x4 s[4] = {};
#pragma unroll
    for (int jt = 0; jt < 4; ++jt) {
#pragma unroll
      for (int kc = 0; kc < 2; ++kc) {
        s16x8 kb = *(const s16x8*)&Ks[cur][sw64(jt * 16 + low, kc * 32 + 8 * g)];
        s[jt] = __builtin_amdgcn_mfma_f32_16x16x32_bf16(qu[kc], kb, s[jt], 0, 0, 0);
      }
    }
    // ---- P = (q+v)·R over the wave's 80-col m-window ----
    f32x4 p[5] = {};
#pragma unroll
    for (int mt = 0; mt < 5; ++mt) {
#pragma unroll
      for (int kc = 0; kc < 2; ++kc) {
        s16x8 rb = *(const s16x8*)&Rs[cur][sw64(lb_w + mt * 16 + low, kc * 32 + 8 * g)];
        p[mt] = __builtin_amdgcn_mfma_f32_16x16x32_bf16(qv[kc], rb, p[mt], 0, 0, 0);
      }
    }
    // ---- rel-shift via shfl + mask ----
#pragma unroll
    for (int r = 0; r < 4; ++r) {
      int iL = 4 * g + r;
      int src = g * 16 + ((low + 15 - iL) & 15);   // D-layout: col=lane&15
      float sh0 = __shfl(p[0][r], src);
      float sh1 = __shfl(p[1][r], src);
      float sh2 = __shfl(p[2][r], src);
      float sh3 = __shfl(p[3][r], src);
      float sh4 = __shfl(p[4][r], src);
      bool lo = (low <= iL);
      float po0 = lo ? sh0 : sh1;
      float po1 = lo ? sh1 : sh2;
      float po2 = lo ? sh2 : sh3;
      float po3 = lo ? sh3 : sh4;
      int lim = TAU_ + i0 + 16 * w + iL;
      s[0][r] = (j0 +  0 + low <= lim) ? (s[0][r] + po0) * 0.125f : -1e30f;
      s[1][r] = (j0 + 16 + low <= lim) ? (s[1][r] + po1) * 0.125f : -1e30f;
      s[2][r] = (j0 + 32 + low <= lim) ? (s[2][r] + po2) * 0.125f : -1e30f;
      s[3][r] = (j0 + 48 + low <= lim) ? (s[3][r] + po3) * 0.125f : -1e30f;
    }
    // ---- online softmax (DPP row-reduce, VALU pipe) ----
#pragma unroll
    for (int r = 0; r < 4; ++r) {
      float mx = fmaxf(fmaxf(s[0][r], s[1][r]), fmaxf(s[2][r], s[3][r]));
      mx = fmaxf(mx, dppmov<0xB1>(mx));    // xor1 (quad_perm)
      mx = fmaxf(mx, dppmov<0x4E>(mx));    // xor2 (quad_perm)
      mx = fmaxf(mx, dppmov<0x124>(mx));   // row_ror:4
      mx = fmaxf(mx, dppmov<0x128>(mx));   // row_ror:8
      float mn = fmaxf(mreg[r], mx);
      float alpha = __expf(mreg[r] - mn);
      mreg[r] = mn;
      float sum = 0.f;
#pragma unroll
      for (int jt = 0; jt < 4; ++jt) {
        float pe = __expf(s[jt][r] - mn);
        s[jt][r] = pe;
        sum += pe;
      }
      sum += dppmov<0xB1>(sum);
      sum += dppmov<0x4E>(sum);
      sum += dppmov<0x124>(sum);
      sum += dppmov<0x128>(sum);
      lreg[r] = lreg[r] * alpha + sum;
      O[0][r] *= alpha; O[1][r] *= alpha; O[2][r] *= alpha; O[3][r] *= alpha;
    }
    // ---- P -> bf16 LDS (C-layout -> A-layout transpose) ----
#pragma unroll
    for (int jt = 0; jt < 4; ++jt)
#pragma unroll
      for (int r = 0; r < 4; ++r)
        Pp[w][sw64(4 * g + r, jt * 16 + low)] = f2bf(s[jt][r]);
    asm volatile("s_waitcnt lgkmcnt(0)" ::: "memory");
    s16x8 pa0 = *(const s16x8*)&Pp[w][sw64(low, 8 * g)];
    s16x8 pa1 = *(const s16x8*)&Pp[w][sw64(low, 32 + 8 * g)];
    // ---- PV ----
#pragma unroll
    for (int dt = 0; dt < 4; ++dt) {
      s16x8 v0 = *(const s16x8*)&Vt[cur][sw64(dt * 16 + low, 8 * g)];
      s16x8 v1 = *(const s16x8*)&Vt[cur][sw64(dt * 16 + low, 32 + 8 * g)];
      O[dt] = __builtin_amdgcn_mfma_f32_16x16x32_bf16(pa0, v0, O[dt], 0, 0, 0);
      O[dt] = __builtin_amdgcn_mfma_f32_16x16x32_bf16(pa1, v1, O[dt], 0, 0, 0);
    }
    if (more) vwrite(cur ^ 1);   // V transpose-write for next tile (late)
    __syncthreads();             // LDS reads done + DMA landed + V writes vis
    cur ^= 1;
  }
  // epilogue: normalize, store bf16 for the out-GEMM
  float inv[4];
#pragma unroll
  for (int r = 0; r < 4; ++r) inv[r] = 1.0f / lreg[r];
#pragma unroll
  for (int dt = 0; dt < 4; ++dt)
#pragma unroll
    for (int r = 0; r < 4; ++r)
      attn[((size_t)(b * T_ + i0 + 16 * w + 4 * g + r)) * 1024 +
           h * 64 + dt * 16 + low] = f2bf(O[dt][r] * inv[r]);
}

// ---------------------------------------------------------------------------
extern "C" void kernel_launch(void* const* d_in, const int* in_sizes, int n_in,
                              void* d_out, int out_size, void* d_ws, size_t ws_size,
                              hipStream_t stream) {
  const float* inputs = (const float*)d_in[0];
  const float* memory = (const float*)d_in[1];
  const float* w_qkv  = (const float*)d_in[2];
  const float* w_pos  = (const float*)d_in[3];
  const float* w_out  = (const float*)d_in[4];
  const float* uvar   = (const float*)d_in[5];
  const float* vvar   = (const float*)d_in[6];
  const float* gamma  = (const float*)d_in[7];
  const float* beta   = (const float*)d_in[8];
  float* out = (float*)d_out;

  // workspace layout, all bf16 (48.2 MB)
  ushort* qkvB = (ushort*)d_ws;                       // 4096*3072
  ushort* xnb  = qkvB + (size_t)4096 * 3072;          // 4096*1024
  ushort* phib = xnb  + (size_t)4096 * 1024;          // 1024*1024
  ushort* RmB  = phib + (size_t)1024 * 1024;          // 1024*1024
  ushort* wqb  = RmB  + (size_t)1024 * 1024;          // 3072*1024
  ushort* wpb  = wqb  + (size_t)3072 * 1024;          // 1024*1024
  ushort* wob  = wpb  + (size_t)1024 * 1024;          // 1024*1024
  ushort* attnb = xnb;                                // reuse after QKV GEMM

  prep_kernel<<<13312, 256, 0, stream>>>(inputs, memory, gamma, beta, xnb,
                                         phib, w_qkv, wqb, w_pos, wpb, w_out, wob);
  qkv_r_gemm<<<832, 256, 0, stream>>>(xnb, wqb, qkvB, phib, wpb, RmB);
  attn_mfma_kernel<<<dim3(B_ * H_ * 8), 256, 0, stream>>>(qkvB, RmB, uvar, vvar, attnb);
  out_gemm<<<128, 256, 0, stream>>>(attnb, wob, out);
}

// Round 8
// 209.147 us; speedup vs baseline: 1.2783x; 1.0099x over previous
//
#include <hip/hip_runtime.h>
#include <math.h>

#define B_   4
#define T_   512
#define TAU_ 512
#define L_   1024
#define DM_  1024
#define H_   16
#define D_   64

typedef short  s16x8 __attribute__((ext_vector_type(8)));   // 8 bf16 MFMA frag
typedef ushort u16x4 __attribute__((ext_vector_type(4)));
typedef float  f32x4 __attribute__((ext_vector_type(4)));

__device__ __forceinline__ ushort f2bf(float x) {   // RNE float->bf16 bits
  uint u = __float_as_uint(x);
  u += 0x7fffu + ((u >> 16) & 1u);
  return (ushort)(u >> 16);
}
__device__ __forceinline__ float bf2f(ushort u) {
  return __uint_as_float(((uint)u) << 16);
}
// XOR-swizzle for bf16 [rows][64] LDS tiles (128B rows): permute 16B slots by row&7
__device__ __forceinline__ int sw64(int row, int col) {
  return row * 64 + (col ^ ((row & 7) << 3));
}

// ---------------------------------------------------------------------------
// Fused preprocessing: [0,4096) LayerNorm rows -> bf16 xn;
// [4096,8192) phi table; [8192,13312) weight fp32->bf16 casts.
// ---------------------------------------------------------------------------
__global__ __launch_bounds__(256) void prep_kernel(
    const float* __restrict__ inp, const float* __restrict__ mem,
    const float* __restrict__ gamma, const float* __restrict__ beta,
    ushort* __restrict__ xn, ushort* __restrict__ phi,
    const float* __restrict__ wq, ushort* __restrict__ wqb,
    const float* __restrict__ wp, ushort* __restrict__ wpb,
    const float* __restrict__ wo, ushort* __restrict__ wob) {
  int blk = blockIdx.x;
  int t = threadIdx.x;
  if (blk < 4096) {                    // ---- LayerNorm ----
    int row = blk;                     // b*L + l
    int b = row >> 10, l = row & 1023;
    const float* src = (l < TAU_)
        ? mem + ((size_t)b * TAU_ + l) * DM_
        : inp + ((size_t)b * T_ + (l - TAU_)) * DM_;
    float4 v = *(const float4*)(src + t * 4);
    float s  = v.x + v.y + v.z + v.w;
    float s2 = v.x * v.x + v.y * v.y + v.z * v.z + v.w * v.w;
#pragma unroll
    for (int off = 32; off > 0; off >>= 1) {
      s  += __shfl_down(s, off);
      s2 += __shfl_down(s2, off);
    }
    __shared__ float red[8];
    __shared__ float stat[2];
    int wid = t >> 6;
    if ((t & 63) == 0) { red[wid * 2] = s; red[wid * 2 + 1] = s2; }
    __syncthreads();
    if (t == 0) {
      float ts  = red[0] + red[2] + red[4] + red[6];
      float ts2 = red[1] + red[3] + red[5] + red[7];
      float mu  = ts * (1.0f / DM_);
      float var = ts2 * (1.0f / DM_) - mu * mu;
      stat[0] = mu;
      stat[1] = 1.0f / sqrtf(var + 1e-5f);
    }
    __syncthreads();
    float mu = stat[0], rstd = stat[1];
    float4 g  = *(const float4*)(gamma + t * 4);
    float4 be = *(const float4*)(beta  + t * 4);
    u16x4 o;
    o[0] = f2bf((v.x - mu) * rstd * g.x + be.x);
    o[1] = f2bf((v.y - mu) * rstd * g.y + be.y);
    o[2] = f2bf((v.z - mu) * rstd * g.z + be.z);
    o[3] = f2bf((v.w - mu) * rstd * g.w + be.w);
    *(u16x4*)(xn + (size_t)row * DM_ + t * 4) = o;
  } else if (blk < 8192) {             // ---- phi ----
    int idx = (blk - 4096) * 256 + t;  // 0 .. 1M-1
    int m = idx >> 10, c = idx & 1023;
    float p = (float)(1023 - m);
    int cc = (c < 512) ? c : c - 512;
    float invf = __expf(-((float)(2 * cc) * (1.0f / 1024.0f)) * 9.210340371976184f);
    float a = p * invf;
    phi[idx] = f2bf((c < 512) ? sinf(a) : cosf(a));
  } else {                             // ---- weight casts ----
    int i = (blk - 8192) * 256 + t;    // float4-group index, < 1310720
    const float* src; ushort* dst; int off;
    if (i < 786432)       { src = wq; dst = wqb; off = i; }
    else if (i < 1048576) { src = wp; dst = wpb; off = i - 786432; }
    else                  { src = wo; dst = wob; off = i - 1048576; }
    float4 v = *(const float4*)(src + (size_t)off * 4);
    u16x4 o = { f2bf(v.x), f2bf(v.y), f2bf(v.z), f2bf(v.w) };
    *(u16x4*)(dst + (size_t)off * 4) = o;
  }
}

// ---------------------------------------------------------------------------
// bf16 MFMA NT GEMM body: m97 structure, 128x128 tile, BK=64.
// ---------------------------------------------------------------------------
template <typename CT>
__device__ __forceinline__ void gemm_nt_body(
    const ushort* __restrict__ A, const ushort* __restrict__ B,
    CT* __restrict__ C, int M, int N, int K, int bx, int by) {
  __shared__ __attribute__((aligned(16))) ushort As[128 * 64];
  __shared__ __attribute__((aligned(16))) ushort Bs[128 * 64];
  int t = threadIdx.x;
  int w = t >> 6, lane = t & 63, g = lane >> 4, low = lane & 15;
  int wr = w >> 1, wc = w & 1;               // wave 2x2 grid, 64x64 each
  int m0 = by * 128, n0 = bx * 128;
  f32x4 acc[4][4] = {};

  for (int kt = 0; kt < K; kt += 64) {
    __syncthreads();                         // prev-iter LDS reads done
#pragma unroll
    for (int q = 0; q < 4; ++q) {
      int c = t + q * 256;                   // 16B chunk id 0..1023
      int row = c >> 3;
      int gslot = (c & 7) ^ (row & 7);       // inverse swizzle on source
      const ushort* ga = A + (size_t)(m0 + row) * K + kt + gslot * 8;
      const ushort* gb = B + (size_t)(n0 + row) * K + kt + gslot * 8;
      __builtin_amdgcn_global_load_lds(
          (const __attribute__((address_space(1))) void*)ga,
          (__attribute__((address_space(3))) void*)&As[(q * 256 + w * 64) * 8],
          16, 0, 0);
      __builtin_amdgcn_global_load_lds(
          (const __attribute__((address_space(1))) void*)gb,
          (__attribute__((address_space(3))) void*)&Bs[(q * 256 + w * 64) * 8],
          16, 0, 0);
    }
    __syncthreads();                         // vmcnt(0) drain: tiles ready

#pragma unroll
    for (int kc = 0; kc < 2; ++kc) {
      s16x8 af[4], bfr[4];
#pragma unroll
      for (int mi = 0; mi < 4; ++mi) {
        int row = wr * 64 + mi * 16 + low;
        af[mi] = *(const s16x8*)&As[row * 64 + (((4 * kc + g) ^ (row & 7)) * 8)];
      }
#pragma unroll
      for (int ni = 0; ni < 4; ++ni) {
        int col = wc * 64 + ni * 16 + low;
        bfr[ni] = *(const s16x8*)&Bs[col * 64 + (((4 * kc + g) ^ (col & 7)) * 8)];
      }
#pragma unroll
      for (int mi = 0; mi < 4; ++mi)
#pragma unroll
        for (int ni = 0; ni < 4; ++ni)
          acc[mi][ni] = __builtin_amdgcn_mfma_f32_16x16x32_bf16(
              af[mi], bfr[ni], acc[mi][ni], 0, 0, 0);
    }
  }
#pragma unroll
  for (int mi = 0; mi < 4; ++mi)
#pragma unroll
    for (int ni = 0; ni < 4; ++ni)
#pragma unroll
      for (int r = 0; r < 4; ++r) {
        int m = m0 + wr * 64 + mi * 16 + 4 * g + r;
        int n = n0 + wc * 64 + ni * 16 + low;
        if constexpr (sizeof(CT) == 2)
          C[(size_t)m * N + n] = f2bf(acc[mi][ni][r]);
        else
          C[(size_t)m * N + n] = acc[mi][ni][r];
      }
}

// ---------------------------------------------------------------------------
// BN=64 variant (128x64 tile): for GEMMs whose 128x128 grid underfills the
// GPU. Wave 2x2 grid, each 64x32 -> acc[4][2]. LDS 24KB.
// ---------------------------------------------------------------------------
template <typename CT>
__device__ __forceinline__ void gemm_nt_body_n64(
    const ushort* __restrict__ A, const ushort* __restrict__ B,
    CT* __restrict__ C, int M, int N, int K, int bx, int by) {
  __shared__ __attribute__((aligned(16))) ushort As[128 * 64];
  __shared__ __attribute__((aligned(16))) ushort Bs[64 * 64];
  int t = threadIdx.x;
  int w = t >> 6, lane = t & 63, g = lane >> 4, low = lane & 15;
  int wr = w >> 1, wc = w & 1;               // each wave: 64 rows x 32 cols
  int m0 = by * 128, n0 = bx * 64;
  f32x4 acc[4][2] = {};

  for (int kt = 0; kt < K; kt += 64) {
    __syncthreads();
#pragma unroll
    for (int q = 0; q < 4; ++q) {            // A: 1024 chunks
      int c = t + q * 256;
      int row = c >> 3;
      int gslot = (c & 7) ^ (row & 7);
      const ushort* ga = A + (size_t)(m0 + row) * K + kt + gslot * 8;
      __builtin_amdgcn_global_load_lds(
          (const __attribute__((address_space(1))) void*)ga,
          (__attribute__((address_space(3))) void*)&As[(q * 256 + w * 64) * 8],
          16, 0, 0);
    }
#pragma unroll
    for (int q = 0; q < 2; ++q) {            // B: 512 chunks
      int c = t + q * 256;
      int row = c >> 3;
      int gslot = (c & 7) ^ (row & 7);
      const ushort* gb = B + (size_t)(n0 + row) * K + kt + gslot * 8;
      __builtin_amdgcn_global_load_lds(
          (const __attribute__((address_space(1))) void*)gb,
          (__attribute__((address_space(3))) void*)&Bs[(q * 256 + w * 64) * 8],
          16, 0, 0);
    }
    __syncthreads();

#pragma unroll
    for (int kc = 0; kc < 2; ++kc) {
      s16x8 af[4], bfr[2];
#pragma unroll
      for (int mi = 0; mi < 4; ++mi) {
        int row = wr * 64 + mi * 16 + low;
        af[mi] = *(const s16x8*)&As[row * 64 + (((4 * kc + g) ^ (row & 7)) * 8)];
      }
#pragma unroll
      for (int ni = 0; ni < 2; ++ni) {
        int col = wc * 32 + ni * 16 + low;
        bfr[ni] = *(const s16x8*)&Bs[col * 64 + (((4 * kc + g) ^ (col & 7)) * 8)];
      }
#pragma unroll
      for (int mi = 0; mi < 4; ++mi)
#pragma unroll
        for (int ni = 0; ni < 2; ++ni)
          acc[mi][ni] = __builtin_amdgcn_mfma_f32_16x16x32_bf16(
              af[mi], bfr[ni], acc[mi][ni], 0, 0, 0);
    }
  }
#pragma unroll
  for (int mi = 0; mi < 4; ++mi)
#pragma unroll
    for (int ni = 0; ni < 2; ++ni)
#pragma unroll
      for (int r = 0; r < 4; ++r) {
        int m = m0 + wr * 64 + mi * 16 + 4 * g + r;
        int n = n0 + wc * 32 + ni * 16 + low;
        if constexpr (sizeof(CT) == 2)
          C[(size_t)m * N + n] = f2bf(acc[mi][ni][r]);
        else
          C[(size_t)m * N + n] = acc[mi][ni][r];
      }
}

// QKV GEMM (768 tiles) + R GEMM (64 tiles) in one 832-block dispatch.
// Bijective XCD swizzle (832 = 8 x 104).
__global__ __launch_bounds__(256) void qkv_r_gemm(
    const ushort* __restrict__ xnb, const ushort* __restrict__ wqb,
    ushort* __restrict__ qkvB,
    const ushort* __restrict__ phib, const ushort* __restrict__ wpb,
    ushort* __restrict__ RmB) {
  int orig = blockIdx.x;
  int id = (orig & 7) * 104 + (orig >> 3);
  if (id < 768)
    gemm_nt_body<ushort>(xnb, wqb, qkvB, 4096, 3072, 1024, id % 24, id / 24);
  else {
    id -= 768;
    gemm_nt_body<ushort>(phib, wpb, RmB, 1024, 1024, 1024, id % 8, id / 8);
  }
}

// out GEMM with 128x64 tiles: 16x16 = 256 blocks = 1/CU (was 128 = half idle).
__global__ __launch_bounds__(256) void out_gemm(
    const ushort* __restrict__ attnb, const ushort* __restrict__ wob,
    float* __restrict__ out) {
  int orig = blockIdx.x;                     // 256 = 8 x 32
  int id = (orig & 7) * 32 + (orig >> 3);
  gemm_nt_body_n64<float>(attnb, wob, out, 2048, 1024, 1024, id % 16, id / 16);
}

// ---------------------------------------------------------------------------
// MFMA bf16 flash attention with rel-shift.
// vs round-7: (1) softmax back to __shfl_xor (DPP was neutral-negative);
// (2) load-balance: co-resident CU pair is (bid, bid+256) which differs only
// in b -> complement bi when b>=2 so each pair sums to 25 tile-iterations.
// V transposed in-kernel (reg-load early, swizzled ds_write late). K/R
// double-buffered via global_load_lds.
// ---------------------------------------------------------------------------
__global__ __launch_bounds__(256) void attn_mfma_kernel(
    const ushort* __restrict__ qkv, const ushort* __restrict__ Rm,
    const float* __restrict__ uvar, const float* __restrict__ vvar,
    ushort* __restrict__ attn) {
  __shared__ __attribute__((aligned(16))) ushort Ks[2][64 * 64];
  __shared__ __attribute__((aligned(16))) ushort Vt[2][64 * 64];
  __shared__ __attribute__((aligned(16))) ushort Rs[2][128 * 64];
  __shared__ __attribute__((aligned(16))) ushort Pp[4][16 * 64];

  int t   = threadIdx.x;
  int w   = t >> 6;          // wave 0..3
  int lw  = t & 63;
  int g   = lw >> 4;         // k-group 0..3
  int low = lw & 15;

  int bid = blockIdx.x;
  int h   = (bid >> 3) & 15;
  int b   = bid >> 7;
  int bi  = (b >= 2) ? (7 - (bid & 7)) : (bid & 7);   // pair-balance: bid &
                                                      // bid+256 sum to 25 tiles
  int i0  = bi * 64;
  int lb_w = 48 - 16 * w;    // wave's P m-window base within Rs

  // K + R staging via global_load_lds (linear LDS dest, pre-swizzled source)
  auto stage_kr = [&](int buf, int tl) {
    int j0s = tl * 64;
#pragma unroll
    for (int q = 0; q < 2; ++q) {
      int c = t + q * 256;                  // 16B chunk id 0..511
      int row = c >> 3;
      int sl = (c & 7) ^ (row & 7);
      const ushort* srck = qkv + (size_t)(b * L_ + j0s + row) * 3072 +
                           1024 + h * 64 + sl * 8;
      __builtin_amdgcn_global_load_lds(
          (const __attribute__((address_space(1))) void*)srck,
          (__attribute__((address_space(3))) void*)&Ks[buf][(q * 256 + w * 64) * 8],
          16, 0, 0);
    }
    int mb = j0s + 448 - i0;
#pragma unroll
    for (int q = 0; q < 4; ++q) {
      int c = t + q * 256;                  // chunk 0..1023
      int row = c >> 3;                     // R row 0..127
      int m = mb + row; m = (m > 1023) ? 1023 : m;
      int sl = (c & 7) ^ (row & 7);
      const ushort* srcr = Rm + (size_t)m * 1024 + h * 64 + sl * 8;
      __builtin_amdgcn_global_load_lds(
          (const __attribute__((address_space(1))) void*)srcr,
          (__attribute__((address_space(3))) void*)&Rs[buf][(q * 256 + w * 64) * 8],
          16, 0, 0);
    }
  };

  // V staging: reg-load (issue early) ...
  int vj  = t & 63;                         // wave-local j column
  int vd0 = (t >> 6) * 8;                   // wave-uniform d base (0,8,16,24)
  float4 vreg[2];
  auto vload = [&](int tl) {
    const ushort* p = qkv + (size_t)(b * L_ + tl * 64 + vj) * 3072 + 2048 + h * 64;
    vreg[0] = *(const float4*)(p + vd0);
    vreg[1] = *(const float4*)(p + vd0 + 32);
  };
  // ... transpose-write late (d rows wave-uniform: 64 lanes x 2B = no conflict)
  auto vwrite = [&](int buf) {
#pragma unroll
    for (int it = 0; it < 2; ++it) {
      ushort vals[8];
      *(float4*)vals = vreg[it];
#pragma unroll
      for (int e = 0; e < 8; ++e) {
        int d = it * 32 + vd0 + e;
        Vt[buf][d * 64 + (vj ^ ((d & 7) << 3))] = vals[e];
      }
    }
  };

  // Q fragments (bf16 source + fp32 u/v), loaded once
  int iq = i0 + 16 * w + low;
  s16x8 qu[2], qv[2];
  {
    const ushort* qrow = qkv + (size_t)(b * L_ + TAU_ + iq) * 3072 + h * 64;
    const float* ur = uvar + h * 64;
    const float* vr = vvar + h * 64;
#pragma unroll
    for (int kc = 0; kc < 2; ++kc) {
      int dbase = kc * 32 + 8 * g;
#pragma unroll
      for (int e = 0; e < 8; ++e) {
        float q = bf2f(qrow[dbase + e]);
        qu[kc][e] = (short)f2bf(q + ur[dbase + e]);
        qv[kc][e] = (short)f2bf(q + vr[dbase + e]);
      }
    }
  }

  f32x4 O[4] = {};
  float mreg[4] = {-INFINITY, -INFINITY, -INFINITY, -INFINITY};
  float lreg[4] = {0.f, 0.f, 0.f, 0.f};

  int ntiles = 9 + bi;       // covers j <= TAU + i0 + 63 exactly
  stage_kr(0, 0);
  vload(0);
  vwrite(0);                 // compiler inserts vmcnt wait on vreg use
  __syncthreads();           // drains DMA + LDS writes: tile 0 ready
  int cur = 0;
  for (int tile = 0; tile < ntiles; ++tile) {
    int j0 = tile * 64;
    bool more = (tile + 1 < ntiles);
    if (more) { stage_kr(cur ^ 1, tile + 1); vload(tile + 1); }

    // ---- QK^T ----
    f32x4 s[4] = {};
#pragma unroll
    for (int jt = 0; jt < 4; ++jt) {
#pragma unroll
      for (int kc = 0; kc < 2; ++kc) {
        s16x8 kb = *(const s16x8*)&Ks[cur][sw64(jt * 16 + low, kc * 32 + 8 * g)];
        s[jt] = __builtin_amdgcn_mfma_f32_16x16x32_bf16(qu[kc], kb, s[jt], 0, 0, 0);
      }
    }
    // ---- P = (q+v)·R over the wave's 80-col m-window ----
    f32x4 p[5] = {};
#pragma unroll
    for (int mt = 0; mt < 5; ++mt) {
#pragma unroll
      for (int kc = 0; kc < 2; ++kc) {
        s16x8 rb = *(const s16x8*)&Rs[cur][sw64(lb_w + mt * 16 + low, kc * 32 + 8 * g)];
        p[mt] = __builtin_amdgcn_mfma_f32_16x16x32_bf16(qv[kc], rb, p[mt], 0, 0, 0);
      }
    }
    // ---- rel-shift via shfl + mask ----
#pragma unroll
    for (int r = 0; r < 4; ++r) {
      int iL = 4 * g + r;
      int src = g * 16 + ((low + 15 - iL) & 15);   // D-layout: col=lane&15
      float sh0 = __shfl(p[0][r], src);
      float sh1 = __shfl(p[1][r], src);
      float sh2 = __shfl(p[2][r], src);
      float sh3 = __shfl(p[3][r], src);
      float sh4 = __shfl(p[4][r], src);
      bool lo = (low <= iL);
      float po0 = lo ? sh0 : sh1;
      float po1 = lo ? sh1 : sh2;
      float po2 = lo ? sh2 : sh3;
      float po3 = lo ? sh3 : sh4;
      int lim = TAU_ + i0 + 16 * w + iL;
      s[0][r] = (j0 +  0 + low <= lim) ? (s[0][r] + po0) * 0.125f : -1e30f;
      s[1][r] = (j0 + 16 + low <= lim) ? (s[1][r] + po1) * 0.125f : -1e30f;
      s[2][r] = (j0 + 32 + low <= lim) ? (s[2][r] + po2) * 0.125f : -1e30f;
      s[3][r] = (j0 + 48 + low <= lim) ? (s[3][r] + po3) * 0.125f : -1e30f;
    }
    // ---- online softmax ----
#pragma unroll
    for (int r = 0; r < 4; ++r) {
      float mx = fmaxf(fmaxf(s[0][r], s[1][r]), fmaxf(s[2][r], s[3][r]));
      mx = fmaxf(mx, __shfl_xor(mx, 1));
      mx = fmaxf(mx, __shfl_xor(mx, 2));
      mx = fmaxf(mx, __shfl_xor(mx, 4));
      mx = fmaxf(mx, __shfl_xor(mx, 8));
      float mn = fmaxf(mreg[r], mx);
      float alpha = __expf(mreg[r] - mn);
      mreg[r] = mn;
      float sum = 0.f;
#pragma unroll
      for (int jt = 0; jt < 4; ++jt) {
        float pe = __expf(s[jt][r] - mn);
        s[jt][r] = pe;
        sum += pe;
      }
      sum += __shfl_xor(sum, 1);
      sum += __shfl_xor(sum, 2);
      sum += __shfl_xor(sum, 4);
      sum += __shfl_xor(sum, 8);
      lreg[r] = lreg[r] * alpha + sum;
      O[0][r] *= alpha; O[1][r] *= alpha; O[2][r] *= alpha; O[3][r] *= alpha;
    }
    // ---- P -> bf16 LDS (C-layout -> A-layout transpose) ----
#pragma unroll
    for (int jt = 0; jt < 4; ++jt)
#pragma unroll
      for (int r = 0; r < 4; ++r)
        Pp[w][sw64(4 * g + r, jt * 16 + low)] = f2bf(s[jt][r]);
    asm volatile("s_waitcnt lgkmcnt(0)" ::: "memory");
    s16x8 pa0 = *(const s16x8*)&Pp[w][sw64(low, 8 * g)];
    s16x8 pa1 = *(const s16x8*)&Pp[w][sw64(low, 32 + 8 * g)];
    // ---- PV ----
#pragma unroll
    for (int dt = 0; dt < 4; ++dt) {
      s16x8 v0 = *(const s16x8*)&Vt[cur][sw64(dt * 16 + low, 8 * g)];
      s16x8 v1 = *(const s16x8*)&Vt[cur][sw64(dt * 16 + low, 32 + 8 * g)];
      O[dt] = __builtin_amdgcn_mfma_f32_16x16x32_bf16(pa0, v0, O[dt], 0, 0, 0);
      O[dt] = __builtin_amdgcn_mfma_f32_16x16x32_bf16(pa1, v1, O[dt], 0, 0, 0);
    }
    if (more) vwrite(cur ^ 1);   // V transpose-write for next tile (late)
    __syncthreads();             // LDS reads done + DMA landed + V writes vis
    cur ^= 1;
  }
  // epilogue: normalize, store bf16 for the out-GEMM
  float inv[4];
#pragma unroll
  for (int r = 0; r < 4; ++r) inv[r] = 1.0f / lreg[r];
#pragma unroll
  for (int dt = 0; dt < 4; ++dt)
#pragma unroll
    for (int r = 0; r < 4; ++r)
      attn[((size_t)(b * T_ + i0 + 16 * w + 4 * g + r)) * 1024 +
           h * 64 + dt * 16 + low] = f2bf(O[dt][r] * inv[r]);
}

// ---------------------------------------------------------------------------
extern "C" void kernel_launch(void* const* d_in, const int* in_sizes, int n_in,
                              void* d_out, int out_size, void* d_ws, size_t ws_size,
                              hipStream_t stream) {
  const float* inputs = (const float*)d_in[0];
  const float* memory = (const float*)d_in[1];
  const float* w_qkv  = (const float*)d_in[2];
  const float* w_pos  = (const float*)d_in[3];
  const float* w_out  = (const float*)d_in[4];
  const float* uvar   = (const float*)d_in[5];
  const float* vvar   = (const float*)d_in[6];
  const float* gamma  = (const float*)d_in[7];
  const float* beta   = (const float*)d_in[8];
  float* out = (float*)d_out;

  // workspace layout, all bf16 (48.2 MB)
  ushort* qkvB = (ushort*)d_ws;                       // 4096*3072
  ushort* xnb  = qkvB + (size_t)4096 * 3072;          // 4096*1024
  ushort* phib = xnb  + (size_t)4096 * 1024;          // 1024*1024
  ushort* RmB  = phib + (size_t)1024 * 1024;          // 1024*1024
  ushort* wqb  = RmB  + (size_t)1024 * 1024;          // 3072*1024
  ushort* wpb  = wqb  + (size_t)3072 * 1024;          // 1024*1024
  ushort* wob  = wpb  + (size_t)1024 * 1024;          // 1024*1024
  ushort* attnb = xnb;                                // reuse after QKV GEMM

  prep_kernel<<<13312, 256, 0, stream>>>(inputs, memory, gamma, beta, xnb,
                                         phib, w_qkv, wqb, w_pos, wpb, w_out, wob);
  qkv_r_gemm<<<832, 256, 0, stream>>>(xnb, wqb, qkvB, phib, wpb, RmB);
  attn_mfma_kernel<<<dim3(B_ * H_ * 8), 256, 0, stream>>>(qkvB, RmB, uvar, vvar, attnb);
  out_gemm<<<256, 256, 0, stream>>>(attnb, wob, out);
}